// Round 6
// baseline (275.737 us; speedup 1.0000x reference)
//
#include <hip/hip_runtime.h>

// ---------------- problem constants ----------------
constexpr int NTOK = 4096;    // B*S
constexpr int DIM  = 512;     // D
constexpr int FF   = 1536;    // F
constexpr int NE   = 8;       // experts

typedef __attribute__((ext_vector_type(8))) short short8;   // 8 bf16 = 4 VGPR
typedef __attribute__((ext_vector_type(4))) float f32x4;    // MFMA acc

static __device__ __forceinline__ unsigned short f2bf(float f) {
    unsigned int x = __float_as_uint(f);
    unsigned int r = x + 0x7fffu + ((x >> 16) & 1u);   // RNE
    return (unsigned short)(r >> 16);
}

// async global->LDS, 16B per lane; LDS dest = wave-uniform base + lane*16
static __device__ __forceinline__ void gload_lds16(const void* g, void* l) {
    __builtin_amdgcn_global_load_lds(
        (const __attribute__((address_space(1))) unsigned int*)g,
        (__attribute__((address_space(3))) unsigned int*)l, 16, 0, 0);
}

// ---------------- router: logits, top-2, softmax weights; also x->bf16 ----------------
__global__ __launch_bounds__(256) void moe_router(
    const float* __restrict__ x, const float* __restrict__ wg,
    int* __restrict__ eidx, float* __restrict__ wts, unsigned short* __restrict__ xbf)
{
    int lane = threadIdx.x & 63;
    int wave = threadIdx.x >> 6;
    int tok  = blockIdx.x * 4 + wave;

    float acc[NE];
#pragma unroll
    for (int e = 0; e < NE; ++e) acc[e] = 0.f;

    const float* xr = x + (size_t)tok * DIM;
    unsigned short* xo = xbf + (size_t)tok * DIM;
#pragma unroll
    for (int i = 0; i < DIM / 64; ++i) {
        int d = i * 64 + lane;
        float xv = xr[d];
        xo[d] = f2bf(xv);
        const float4* wr = (const float4*)(wg + (size_t)d * NE);
        float4 w0 = wr[0], w1 = wr[1];
        acc[0] += xv * w0.x; acc[1] += xv * w0.y; acc[2] += xv * w0.z; acc[3] += xv * w0.w;
        acc[4] += xv * w1.x; acc[5] += xv * w1.y; acc[6] += xv * w1.z; acc[7] += xv * w1.w;
    }
#pragma unroll
    for (int e = 0; e < NE; ++e) {
#pragma unroll
        for (int off = 32; off >= 1; off >>= 1)
            acc[e] += __shfl_xor(acc[e], off, 64);
    }
    if (lane == 0) {
        int i0 = 0; float m0 = acc[0];
#pragma unroll
        for (int e = 1; e < NE; ++e) if (acc[e] > m0) { m0 = acc[e]; i0 = e; }
        int i1 = -1; float m1 = -3.4e38f;
#pragma unroll
        for (int e = 0; e < NE; ++e) if (e != i0 && acc[e] > m1) { m1 = acc[e]; i1 = e; }
        float e1 = expf(m1 - m0);
        float s  = 1.f + e1;
        int s0 = tok * 2, s1 = tok * 2 + 1;
        wts[s0] = 1.f / s;
        wts[s1] = e1 / s;
        eidx[s0] = i0;
        eidx[s1] = i1;
    }
}

// ---------------- phase 1: per-chunk per-expert counts (32 chunks x 256 slots) ----------------
__global__ __launch_bounds__(256) void moe_count(
    const int* __restrict__ eidx, int* __restrict__ pcnt)
{
    __shared__ int s_wc[4][8];
    int tid = threadIdx.x, lane = tid & 63, wv = tid >> 6;
    int e = eidx[blockIdx.x * 256 + tid];
#pragma unroll
    for (int e0 = 0; e0 < 8; ++e0) {
        unsigned long long bal = __ballot(e == e0);
        if (lane == 0) s_wc[wv][e0] = __popcll(bal);
    }
    __syncthreads();
    if (tid < 8)
        pcnt[blockIdx.x * 8 + tid] = s_wc[0][tid] + s_wc[1][tid] + s_wc[2][tid] + s_wc[3][tid];
}

// ---------------- phase 2: scatter slots into compact expert-sorted list ----------------
__global__ __launch_bounds__(256) void moe_scatter(
    const int* __restrict__ eidx, const int* __restrict__ pcnt,
    int* __restrict__ clist, int* __restrict__ cnt, int* __restrict__ ebase)
{
    __shared__ int s_all[256];
    __shared__ int s_wc[4][8];
    int tid = threadIdx.x, bx = blockIdx.x;
    int lane = tid & 63, wv = tid >> 6;
    s_all[tid] = pcnt[tid];
    int slot = bx * 256 + tid;
    int e = eidx[slot];
    int myoff = 0;
#pragma unroll
    for (int e0 = 0; e0 < 8; ++e0) {
        unsigned long long bal = __ballot(e == e0);
        if (lane == 0) s_wc[wv][e0] = __popcll(bal);
        if (e == e0) myoff = __popcll(bal & ((1ull << lane) - 1ull));
    }
    __syncthreads();
    int base = 0;
#pragma unroll
    for (int ep = 0; ep < 8; ++ep) {
        int t = 0;
        for (int b = 0; b < 32; ++b) t += s_all[b * 8 + ep];
        if (ep < e) base += (t + 7) & ~7;
    }
    int cbase = 0;
    for (int b = 0; b < bx; ++b) cbase += s_all[b * 8 + e];
    int wbase = 0;
    for (int w = 0; w < wv; ++w) wbase += s_wc[w][e];
    clist[base + cbase + wbase + myoff] = slot;
    if (bx == 0 && tid == 0) {
        int eb = 0;
        for (int ep = 0; ep < 8; ++ep) {
            int t = 0;
            for (int b = 0; b < 32; ++b) t += s_all[b * 8 + ep];
            cnt[ep] = t;
            ebase[ep] = eb;
            eb += (t + 7) & ~7;
        }
    }
}

// ---------------- transpose fp32 [R][C] -> bf16 [C][R] PRE-SWIZZLED, dual tensor ----------------
__global__ __launch_bounds__(256) void transpose_cvt2(
    const float* __restrict__ inA, unsigned short* __restrict__ outA,
    const float* __restrict__ inB, unsigned short* __restrict__ outB,
    int R, int C)
{
    __shared__ float tile[64][65];
    int c0 = blockIdx.x * 64, r0 = blockIdx.y * 64, z = blockIdx.z;
    const float* in      = (z < 8) ? inA  : inB;
    unsigned short* out  = (z < 8) ? outA : outB;
    int zz = z & 7;
    const float* ip = in + (size_t)zz * R * C;
    char* op = (char*)(out + (size_t)zz * R * C);

    int tr = threadIdx.x >> 4;          // 0..15
    int tc = (threadIdx.x & 15) * 4;    // 0,4,..,60
#pragma unroll
    for (int p = 0; p < 4; ++p) {
        int r = p * 16 + tr;
        float4 v = *(const float4*)(ip + (size_t)(r0 + r) * C + c0 + tc);
        tile[r][tc + 0] = v.x; tile[r][tc + 1] = v.y;
        tile[r][tc + 2] = v.z; tile[r][tc + 3] = v.w;
    }
    __syncthreads();
#pragma unroll
    for (int p = 0; p < 4; ++p) {
        int c = p * 16 + tr;            // output row = original col
        ushort4 o;
        o.x = f2bf(tile[tc + 0][c]);
        o.y = f2bf(tile[tc + 1][c]);
        o.z = f2bf(tile[tc + 2][c]);
        o.w = f2bf(tile[tc + 3][c]);
        int cb = ((r0 + tc) * 2) ^ ((c & 7) << 4);   // XOR touches bits 4-6 only
        *(ushort4*)(op + (size_t)(c0 + c) * (R * 2) + cb) = o;
    }
}

// ---------------- FFN1: act_c[crow][f] = silu(x W1) * (x W3 + b3) ----------------
// 1D grid, physical id p = e + 8*(mb*12 + n): all blocks of expert e -> XCD e
// (p%8 round-robin), so W1+W3[e] (3.1 MB) stays L2-resident and the 12 n-blocks
// sharing one A-tile are adjacent in that XCD's dispatch sequence.
__global__ __launch_bounds__(256, 3) void moe_ffn1(
    const unsigned short* __restrict__ xbf,   // [NTOK][D] bf16 linear
    const unsigned short* __restrict__ w1t,   // [E][F][D] bf16 pre-swizzled
    const unsigned short* __restrict__ w3t,   // [E][F][D] bf16 pre-swizzled
    const float* __restrict__ b3,             // [E][F]
    const int* __restrict__ cnt, const int* __restrict__ ebase,
    const int* __restrict__ clist,
    unsigned short* __restrict__ actc)        // [8256][F] bf16 pre-swizzled
{
    int p    = blockIdx.x;
    int e    = p & 7;
    int q    = p >> 3;
    int mb   = q / 12;
    int n0   = (q - mb * 12) * 128;
    int ce   = cnt[e];
    int row0 = mb * 128;
    if (row0 >= ce) return;
    int eb   = ebase[e];

    __shared__ __attribute__((aligned(16))) char smem[49152];
    __shared__ int s_slot[128];
    char* sA  = smem;                 // 16 KiB: A 128x128B
    char* sB1 = smem + 16384;         // 16 KiB
    char* sB3 = smem + 32768;         // 16 KiB

    int tid = threadIdx.x;
    if (tid < 128) {
        int r = row0 + tid;
        s_slot[tid] = (r < ce) ? clist[eb + r] : clist[eb + row0];
    }
    __syncthreads();

    int lane = tid & 63, wv = tid >> 6;
    int wm = wv >> 1, wn = wv & 1;
    int lrow = lane >> 3;             // 0..7
    int lcol = (lane & 7) * 16;       // 0..112
    int aswz = lcol ^ (lrow << 4);    // per-lane source swizzle for linear xbf

    const char* aSrc[4]; const char* b1Src[4]; const char* b3Src[4];
#pragma unroll
    for (int i = 0; i < 4; ++i) {
        int rr = i * 32 + wv * 8 + lrow;
        aSrc[i] = (const char*)xbf + (size_t)(s_slot[rr] >> 1) * (DIM * 2) + aswz;
        size_t rb = ((size_t)e * FF + n0 + rr) * (DIM * 2) + lcol;   // weights pre-swizzled
        b1Src[i] = (const char*)w1t + rb;
        b3Src[i] = (const char*)w3t + rb;
    }

    f32x4 acch[4][4], accg[4][4];
#pragma unroll
    for (int i = 0; i < 4; ++i)
#pragma unroll
        for (int j = 0; j < 4; ++j) { acch[i][j] = (f32x4)0.f; accg[i][j] = (f32x4)0.f; }

    for (int kc = 0; kc < DIM * 2; kc += 128) {
#pragma unroll
        for (int i = 0; i < 4; ++i) {
            int ro = (i * 32 + wv * 8) * 128;
            gload_lds16(aSrc[i]  + kc, sA  + ro);
            gload_lds16(b1Src[i] + kc, sB1 + ro);
            gload_lds16(b3Src[i] + kc, sB3 + ro);
        }
        __syncthreads();

#pragma unroll
        for (int ks = 0; ks < 2; ++ks) {
            short8 af[4], b1f[4], b3f[4];
#pragma unroll
            for (int mi = 0; mi < 4; ++mi) {
                int row = wm * 64 + mi * 16 + (lane & 15);
                int ba  = row * 128 + ((ks * 64 + (lane >> 4) * 16) ^ ((row & 7) << 4));
                af[mi] = *(const short8*)(sA + ba);
            }
#pragma unroll
            for (int ni = 0; ni < 4; ++ni) {
                int row = wn * 64 + ni * 16 + (lane & 15);
                int ba  = row * 128 + ((ks * 64 + (lane >> 4) * 16) ^ ((row & 7) << 4));
                b1f[ni] = *(const short8*)(sB1 + ba);
                b3f[ni] = *(const short8*)(sB3 + ba);
            }
#pragma unroll
            for (int mi = 0; mi < 4; ++mi)
#pragma unroll
                for (int ni = 0; ni < 4; ++ni) {
                    acch[mi][ni] = __builtin_amdgcn_mfma_f32_16x16x32_bf16(af[mi], b1f[ni], acch[mi][ni], 0, 0, 0);
                    accg[mi][ni] = __builtin_amdgcn_mfma_f32_16x16x32_bf16(af[mi], b3f[ni], accg[mi][ni], 0, 0, 0);
                }
        }
        __syncthreads();   // also guards sE reuse below
    }

    // epilogue: silu(h)*(g+b3) -> LDS tile (bf16 [128][128], 256B rows) -> coalesced stores
    char* sE = smem;
#pragma unroll
    for (int ni = 0; ni < 4; ++ni) {
        int col = wn * 64 + ni * 16 + (lane & 15);
        float b3v = b3[e * FF + n0 + col];
#pragma unroll
        for (int mi = 0; mi < 4; ++mi) {
            int rbase = wm * 64 + mi * 16 + (lane >> 4) * 4;
#pragma unroll
            for (int r = 0; r < 4; ++r) {
                float h = acch[mi][ni][r];
                float g = accg[mi][ni][r] + b3v;
                float a = (h / (1.f + __expf(-h))) * g;
                *(unsigned short*)(sE + (rbase + r) * 256 + col * 2) = f2bf(a);
            }
        }
    }
    __syncthreads();

    int lim = ce - row0;
#pragma unroll
    for (int it = 0; it < 8; ++it) {
        int chunk = it * 256 + tid;        // 2048 chunks = 128 rows x 16
        int row = chunk >> 4, c8 = chunk & 15;
        if (row < lim) {
            int crow = eb + row0 + row;
            // bake XOR-swizzle into act_c so ffn2 stages with plain linear offsets
            size_t dst = (size_t)crow * (FF * 2) + n0 * 2 + ((c8 * 16) ^ ((crow & 7) << 4));
            *(short8*)((char*)actc + dst) = *(const short8*)(sE + row * 256 + c8 * 16);
        }
    }
}

// ---------------- FFN2: out[tok][d] += w_slot * (act W2)  (atomic combine) ----------------
// 1D grid, p = e + 8*(mb*8 + n): expert->XCD pinning as in ffn1.
__global__ __launch_bounds__(256) void moe_ffn2(
    const unsigned short* __restrict__ actc,  // [8256][F] bf16 pre-swizzled
    const unsigned short* __restrict__ w2t,   // [E][D][F] bf16 pre-swizzled
    const int* __restrict__ cnt, const int* __restrict__ ebase,
    const int* __restrict__ clist, const float* __restrict__ wts,
    float* __restrict__ out)                  // [NTOK][D] fp32, pre-zeroed
{
    int p    = blockIdx.x;
    int e    = p & 7;
    int q    = p >> 3;
    int mb   = q >> 3;
    int n0   = (q & 7) * 64;
    int ce   = cnt[e];
    int row0 = mb * 128;
    if (row0 >= ce) return;
    int eb   = ebase[e];

    __shared__ __attribute__((aligned(16))) char smem[24576];
    __shared__ int   s_slot[128];
    __shared__ float s_w[128];
    char* sA = smem;                  // 16 KiB
    char* sB = smem + 16384;          // 8 KiB

    int tid = threadIdx.x;
    if (tid < 128) {
        int r  = row0 + tid;
        int sl = (r < ce) ? clist[eb + r] : clist[eb + row0];
        s_slot[tid] = sl;
        s_w[tid]    = wts[sl];
    }
    __syncthreads();

    int lane = tid & 63, wv = tid >> 6;
    int wm = wv >> 1, wn = wv & 1;
    int lrow = lane >> 3;
    int lcol = (lane & 7) * 16;

    const char* aSrc[4];
#pragma unroll
    for (int i = 0; i < 4; ++i) {
        int rr = i * 32 + wv * 8 + lrow;
        int cr = (row0 + rr < ce) ? (eb + row0 + rr) : (eb + row0);  // clamp: stay in-bounds
        aSrc[i] = (const char*)actc + (size_t)cr * (FF * 2) + lcol;  // actc pre-swizzled
    }
    const char* bSrc[2];
#pragma unroll
    for (int i = 0; i < 2; ++i) {
        int rr = i * 32 + wv * 8 + lrow;
        bSrc[i] = (const char*)w2t + ((size_t)e * DIM + n0 + rr) * (FF * 2) + lcol;
    }

    f32x4 acc[4][2];
#pragma unroll
    for (int i = 0; i < 4; ++i)
#pragma unroll
        for (int j = 0; j < 2; ++j) acc[i][j] = (f32x4)0.f;

    for (int kc = 0; kc < FF * 2; kc += 128) {
#pragma unroll
        for (int i = 0; i < 4; ++i)
            gload_lds16(aSrc[i] + kc, sA + (i * 32 + wv * 8) * 128);
#pragma unroll
        for (int i = 0; i < 2; ++i)
            gload_lds16(bSrc[i] + kc, sB + (i * 32 + wv * 8) * 128);
        __syncthreads();

#pragma unroll
        for (int ks = 0; ks < 2; ++ks) {
            short8 af[4], bf[2];
#pragma unroll
            for (int mi = 0; mi < 4; ++mi) {
                int row = wm * 64 + mi * 16 + (lane & 15);
                int ba  = row * 128 + ((ks * 64 + (lane >> 4) * 16) ^ ((row & 7) << 4));
                af[mi] = *(const short8*)(sA + ba);
            }
#pragma unroll
            for (int ni = 0; ni < 2; ++ni) {
                int row = wn * 32 + ni * 16 + (lane & 15);
                int ba  = row * 128 + ((ks * 64 + (lane >> 4) * 16) ^ ((row & 7) << 4));
                bf[ni] = *(const short8*)(sB + ba);
            }
#pragma unroll
            for (int mi = 0; mi < 4; ++mi)
#pragma unroll
                for (int ni = 0; ni < 2; ++ni)
                    acc[mi][ni] = __builtin_amdgcn_mfma_f32_16x16x32_bf16(af[mi], bf[ni], acc[mi][ni], 0, 0, 0);
        }
        __syncthreads();
    }

    // epilogue: scale by routing weight, atomically accumulate into out.
    // Exactly 2 contributions per out element (top-2) and fp32 add is
    // commutative for 2 addends -> deterministic result.
#pragma unroll
    for (int mi = 0; mi < 4; ++mi) {
#pragma unroll
        for (int r = 0; r < 4; ++r) {
            int rg = wm * 64 + mi * 16 + (lane >> 4) * 4 + r;
            if (row0 + rg < ce) {
                float w   = s_w[rg];
                int   tok = s_slot[rg] >> 1;
#pragma unroll
                for (int ni = 0; ni < 2; ++ni) {
                    int dd = n0 + wn * 32 + ni * 16 + (lane & 15);
                    atomicAdd(&out[(size_t)tok * DIM + dd], acc[mi][ni][r] * w);
                }
            }
        }
    }
}

// ---------------- launcher ----------------
extern "C" void kernel_launch(void* const* d_in, const int* in_sizes, int n_in,
                              void* d_out, int out_size, void* d_ws, size_t ws_size,
                              hipStream_t stream)
{
    const float* x  = (const float*)d_in[0];
    const float* wg = (const float*)d_in[1];
    const float* w1 = (const float*)d_in[2];
    const float* w2 = (const float*)d_in[3];
    const float* w3 = (const float*)d_in[4];
    const float* b3 = (const float*)d_in[5];
    float* out = (float*)d_out;
    char*  ws  = (char*)d_ws;

    // small control block
    int*   cnt   = (int*)(ws + 0);        // 8 int
    int*   ebase = (int*)(ws + 64);       // 8 int
    int*   pcnt  = (int*)(ws + 256);      // 256 int
    int*   eidx  = (int*)(ws + 2048);     // 8192 int
    float* wts   = (float*)(ws + 2048 + 32768);            // 8192 f
    int*   clist = (int*)(ws + 2048 + 65536);              // 8256 int
    constexpr size_t OFF_BIG = 102400;
    constexpr size_t WB = (size_t)NE * DIM * FF * 2;       // bytes per weight tensor (bf16)
    unsigned short* w2t  = (unsigned short*)(ws + OFF_BIG);            // 12.58 MB
    unsigned short* w1t  = (unsigned short*)(ws + OFF_BIG + WB);       // 12.58 MB
    unsigned short* w3t  = (unsigned short*)(ws + OFF_BIG + 2 * WB);   // 12.58 MB
    unsigned short* actc = (unsigned short*)(ws + OFF_BIG + 3 * WB);   // 8256*3072B = 25.4 MB
    unsigned short* xbf  = w2t;                 // alias: 4 MB, dead before w2 transpose

    hipMemsetAsync(out, 0, (size_t)NTOK * DIM * sizeof(float), stream);

    moe_router <<<NTOK / 4, 256, 0, stream>>>(x, wg, eidx, wts, xbf);
    moe_count  <<<32, 256, 0, stream>>>(eidx, pcnt);
    moe_scatter<<<32, 256, 0, stream>>>(eidx, pcnt, clist, cnt, ebase);

    dim3 tgA(FF / 64, DIM / 64, 16);   // W1,W3: [512][1536] -> [1536][512]
    transpose_cvt2<<<tgA, 256, 0, stream>>>(w1, w1t, w3, w3t, DIM, FF);

    // ffn1: 8 experts x 32 mb x 12 n, expert->XCD pinned via p = e + 8*q
    moe_ffn1<<<NE * 32 * 12, 256, 0, stream>>>(xbf, w1t, w3t, b3, cnt, ebase, clist, actc);

    dim3 tgB(DIM / 64, FF / 64, 8);    // W2: [1536][512] -> [512][1536], overwrites xbf
    transpose_cvt2<<<tgB, 256, 0, stream>>>(w2, w2t, w2, w2t, FF, DIM);

    // ffn2: 8 experts x 32 mb x 8 n, expert->XCD pinned; atomic combine into out
    moe_ffn2<<<NE * 32 * 8, 256, 0, stream>>>(actc, w2t, cnt, ebase, clist, wts, out);
}